// Round 1
// 958.414 us; speedup vs baseline: 1.4967x; 1.4967x over previous
//
#include <hip/hip_runtime.h>
#include <math.h>

#define NN 100000
#define NE 1000000
#define NR 1000
#define DD 100
#define OUTC 600
#define EPS 1e-12f
#define CHUNK 16   // edges per wave pass: 16 groups x 4 lanes

__device__ inline float wave_sum(float v) {
#pragma unroll
    for (int o = 32; o > 0; o >>= 1) v += __shfl_down(v, o, 64);
    return __shfl(v, 0, 64);
}
// reduce across the 16 groups (lane bits 2..5); result broadcast to all lanes
__device__ inline float grp_sum(float v) {
    v += __shfl_xor(v, 4, 64);
    v += __shfl_xor(v, 8, 64);
    v += __shfl_xor(v, 16, 64);
    v += __shfl_xor(v, 32, 64);
    return v;
}
__device__ inline float grp_max(float v) {
    v = fmaxf(v, __shfl_xor(v, 4, 64));
    v = fmaxf(v, __shfl_xor(v, 8, 64));
    v = fmaxf(v, __shfl_xor(v, 16, 64));
    v = fmaxf(v, __shfl_xor(v, 32, 64));
    return v;
}

// row_ptr[n] = lower_bound(dst, n); dst sorted ascending. row_ptr[NN] = NE.
__global__ void k_rowptr(const int* __restrict__ dst, int* __restrict__ row_ptr) {
    int n = blockIdx.x * blockDim.x + threadIdx.x;
    if (n > NN) return;
    int lo = 0, hi = NE;
    while (lo < hi) {
        int mid = (lo + hi) >> 1;
        if (dst[mid] < n) lo = mid + 1; else hi = mid;
    }
    row_ptr[n] = lo;
}

// rel_norm[r] = rel_emb[r] / max(||rel_emb[r]||, EPS); one wave per relation
__global__ void k_relnorm(const float* __restrict__ rel_emb, float* __restrict__ rel_norm) {
    int w = (blockIdx.x * blockDim.x + threadIdx.x) >> 6;
    int lane = threadIdx.x & 63;
    if (w >= NR) return;
    const float* r = rel_emb + w * DD;
    float v0 = r[lane];
    float v1 = (lane + 64 < DD) ? r[lane + 64] : 0.f;
    float ss = wave_sum(v0 * v0 + v1 * v1);
    float sc = 1.f / fmaxf(sqrtf(ss), EPS);
    float* o = rel_norm + w * DD;
    o[lane] = v0 * sc;
    if (lane + 64 < DD) o[lane + 64] = v1 * sc;
}

// per-relation dots: rdot[r] = <rel_norm[r], w_r>, rwn[r] = <rel_norm[r], w_n>
__global__ void k_relv(const float* __restrict__ rel_norm, const float* __restrict__ k3d,
                       float* __restrict__ rdot, float* __restrict__ rwn) {
    int w = (blockIdx.x * blockDim.x + threadIdx.x) >> 6;
    int lane = threadIdx.x & 63;
    if (w >= NR) return;
    const float* r = rel_norm + w * DD;
    float r0 = r[lane];
    float r1 = (lane + 64 < DD) ? r[lane + 64] : 0.f;
    float wr1 = 0.f, wn1 = 0.f;
    float wr0 = k3d[2 * DD + lane], wn0 = k3d[DD + lane];
    if (lane + 64 < DD) { wr1 = k3d[2 * DD + lane + 64]; wn1 = k3d[DD + lane + 64]; }
    float rd = wave_sum(r0 * wr0 + r1 * wr1);
    float rn = wave_sum(r0 * wn0 + r1 * wn1);
    if (lane == 0) { rdot[w] = rd; rwn[w] = rn; }
}

// tanh(segment-mean of table[idx[e]]) over dst segments. One wave per node,
// 16 edges gathered in parallel (4 lanes each, 6xfloat4 + 1 scalar per lane),
// parked in LDS, then accumulated full-wave in the dim-per-lane layout.
// Also fuses the layer-0 node dots (sdot/ndot) in the epilogue.
__global__ __launch_bounds__(256) void k_segmean(
        const float* __restrict__ table, const int* __restrict__ idx,
        const int* __restrict__ row_ptr, const float* __restrict__ k3d,
        float* __restrict__ sdot, float* __restrict__ ndot,
        float* __restrict__ F, long long fstride,
        float* __restrict__ outcol, int dup) {
    __shared__ float s_buf[4][CHUNK][DD];
    int wid = threadIdx.x >> 6;
    int lane = threadIdx.x & 63;
    int g = lane >> 2, sb = lane & 3;
    int n = blockIdx.x * 4 + wid;
    if (n >= NN) return;
    int beg = row_ptr[n], end = row_ptr[n + 1];
    float a0 = 0.f, a1 = 0.f;
    for (int cb = beg; cb < end; cb += CHUNK) {
        int cnt = min(CHUNK, end - cb);
        int e = cb + ((g < cnt) ? g : cnt - 1);   // clamp; extra slots never read
        int t = idx[e];
        const float* row = table + (size_t)t * DD;
        const float4* r4 = (const float4*)row;
        float4* d4 = (float4*)(&s_buf[wid][g][0]);
#pragma unroll
        for (int k = 0; k < 6; ++k) d4[4 * k + sb] = r4[4 * k + sb];
        s_buf[wid][g][96 + sb] = row[96 + sb];
        for (int j = 0; j < cnt; ++j) {
            a0 += s_buf[wid][j][lane];
            if (lane + 64 < DD) a1 += s_buf[wid][j][lane + 64];
        }
    }
    float inv = 1.f / fmaxf((float)(end - beg), 1.f);
    float o0 = tanhf(a0 * inv);
    float o1 = (lane + 64 < DD) ? tanhf(a1 * inv) : 0.f;
    float* f = F + (size_t)n * fstride;
    f[lane] = o0;
    if (lane + 64 < DD) f[lane + 64] = o1;
    if (dup) {
        float* o = outcol + (size_t)n * OUTC;
        o[lane] = o0;
        if (lane + 64 < DD) o[lane + 64] = o1;
    }
    // fused node dots (layer 0)
    float ws0 = k3d[lane], wn0 = k3d[DD + lane];
    float ws1 = 0.f, wn1 = 0.f;
    if (lane + 64 < DD) { ws1 = k3d[lane + 64]; wn1 = k3d[DD + lane + 64]; }
    float sdv = wave_sum(o0 * ws0 + o1 * ws1);
    float ndv = wave_sum(o0 * wn0 + o1 * wn1);
    if (lane == 0) { sdot[n] = sdv; ndot[n] = ndv; }
}

// Fused layer: logits + segment softmax (online) + aggregate. One wave per
// node; each CHUNK processes 16 edges in PARALLEL: group g (4 lanes) owns
// edge cb+g, gathers F[src] and rel_norm[erel] slices into registers,
// reduces the Householder dot within the group (2 shuffles), parks the
// reflected row in LDS, then the whole wave does the softmax-weighted
// accumulate in the dim-per-lane layout. Optionally fuses the next layer's
// node dots into sdot_o/ndot_o (separate buffers: concurrent waves still
// read this layer's ndot).
__global__ __launch_bounds__(256) void k_layer(
        const float* __restrict__ F, long long fstride,
        const float* __restrict__ rel_norm,
        const int* __restrict__ src, const int* __restrict__ erel,
        const int* __restrict__ row_ptr,
        const float* __restrict__ sdot, const float* __restrict__ ndot,
        const float* __restrict__ rdot, const float* __restrict__ rwn,
        const float* __restrict__ k3d_next,
        float* __restrict__ sdot_o, float* __restrict__ ndot_o,
        float* __restrict__ Fnext, long long fnstride,
        float* __restrict__ outcol, int dup) {
    __shared__ float s_nei[4][CHUNK][DD];
    int wid = threadIdx.x >> 6;
    int lane = threadIdx.x & 63;
    int g = lane >> 2, sb = lane & 3;
    int n = blockIdx.x * 4 + wid;
    if (n >= NN) return;
    int beg = row_ptr[n], end = row_ptr[n + 1];
    float sd = sdot[n];
    float acc0 = 0.f, acc1 = 0.f;
    float m_run = -INFINITY, l_run = 0.f;
    for (int cb = beg; cb < end; cb += CHUNK) {
        int cnt = min(CHUNK, end - cb);
        bool act = (g < cnt);
        int e = cb + (act ? g : cnt - 1);          // clamp keeps loads in-bounds
        int s_e = src[e];
        int r_e = erel[e];
        float nd = ndot[s_e];
        float rd = rdot[r_e];
        float rw = rwn[r_e];
        const float* frow = F + (size_t)s_e * fstride;
        const float* rrow = rel_norm + (size_t)r_e * DD;
        const float4* f4 = (const float4*)frow;
        const float4* r4 = (const float4*)rrow;
        float4 fv[6], rv[6];
#pragma unroll
        for (int k = 0; k < 6; ++k) { fv[k] = f4[4 * k + sb]; rv[k] = r4[4 * k + sb]; }
        float ft = frow[96 + sb];
        float rt = rrow[96 + sb];
        float p = ft * rt;
#pragma unroll
        for (int k = 0; k < 6; ++k)
            p += fv[k].x * rv[k].x + fv[k].y * rv[k].y + fv[k].z * rv[k].z + fv[k].w * rv[k].w;
        p += __shfl_xor(p, 1, 64);
        p += __shfl_xor(p, 2, 64);                 // 4-lane group dot complete
        float c = 2.f * p;
        float4* d4 = (float4*)(&s_nei[wid][g][0]);
#pragma unroll
        for (int k = 0; k < 6; ++k) {
            float4 nv;
            nv.x = fv[k].x - c * rv[k].x;
            nv.y = fv[k].y - c * rv[k].y;
            nv.z = fv[k].z - c * rv[k].z;
            nv.w = fv[k].w - c * rv[k].w;
            d4[4 * k + sb] = nv;
        }
        s_nei[wid][g][96 + sb] = ft - c * rt;
        float lg = act ? (sd + nd - c * rw + rd) : -INFINITY;
        // online softmax update over this chunk
        float mc = grp_max(lg);
        float m_new = fmaxf(m_run, mc);
        float scale = __expf(m_run - m_new);       // exp(-inf)=0 on first chunk
        acc0 *= scale; acc1 *= scale; l_run *= scale;
        float w_l = act ? __expf(lg - m_new) : 0.f;
        l_run += grp_sum(w_l);                     // groups hold w uniformly per sub
        m_run = m_new;
        for (int j = 0; j < cnt; ++j) {
            float w = __shfl(w_l, j << 2, 64);
            acc0 += w * s_nei[wid][j][lane];
            if (lane + 64 < DD) acc1 += w * s_nei[wid][j][lane + 64];
        }
    }
    float o0 = 0.f, o1 = 0.f;
    if (end > beg) {
        float inv = 1.f / l_run;
        o0 = tanhf(acc0 * inv);
        o1 = tanhf(acc1 * inv);
    }
    if (lane + 64 >= DD) o1 = 0.f;
    float* fo = Fnext + (size_t)n * fnstride;
    fo[lane] = o0;
    if (lane + 64 < DD) fo[lane + 64] = o1;
    if (dup) {
        float* oc = outcol + (size_t)n * OUTC;
        oc[lane] = o0;
        if (lane + 64 < DD) oc[lane + 64] = o1;
    }
    if (k3d_next) {
        float ws0 = k3d_next[lane], wn0 = k3d_next[DD + lane];
        float ws1 = 0.f, wn1 = 0.f;
        if (lane + 64 < DD) { ws1 = k3d_next[lane + 64]; wn1 = k3d_next[DD + lane + 64]; }
        float sdv = wave_sum(o0 * ws0 + o1 * ws1);
        float ndv = wave_sum(o0 * wn0 + o1 * wn1);
        if (lane == 0) { sdot_o[n] = sdv; ndot_o[n] = ndv; }
    }
}

extern "C" void kernel_launch(void* const* d_in, const int* in_sizes, int n_in,
                              void* d_out, int out_size, void* d_ws, size_t ws_size,
                              hipStream_t stream) {
    const float* ent_emb = (const float*)d_in[0];
    const float* rel_emb = (const float*)d_in[1];
    const float* attn_e  = (const float*)d_in[2];
    const float* attn_r  = (const float*)d_in[3];
    const int*   src     = (const int*)d_in[4];
    const int*   dst     = (const int*)d_in[5];
    const int*   erel    = (const int*)d_in[6];
    float* out = (float*)d_out;

    char* ws = (char*)d_ws;
    size_t off = 0;
    auto alloc = [&](size_t bytes) -> void* {
        void* p = ws + off;
        off = (off + bytes + 255) & ~(size_t)255;
        return p;
    };
    int*   row_ptr  = (int*)alloc((NN + 1) * sizeof(int));
    float* rel_norm = (float*)alloc((size_t)NR * DD * sizeof(float));
    float* sdotA    = (float*)alloc(NN * sizeof(float));
    float* ndotA    = (float*)alloc(NN * sizeof(float));
    float* sdotB    = (float*)alloc(NN * sizeof(float));
    float* ndotB    = (float*)alloc(NN * sizeof(float));
    float* rdot     = (float*)alloc(NR * sizeof(float));
    float* rwn      = (float*)alloc(NR * sizeof(float));
    float* featsA   = (float*)alloc((size_t)NN * DD * sizeof(float));
    float* featsB   = (float*)alloc((size_t)NN * DD * sizeof(float));
    bool compact = (off <= ws_size);

    hipLaunchKernelGGL(k_rowptr, dim3((NN + 256) / 256), dim3(256), 0, stream, dst, row_ptr);
    hipLaunchKernelGGL(k_relnorm, dim3(NR * 64 / 256), dim3(256), 0, stream, rel_emb, rel_norm);

    for (int enc = 0; enc < 2; ++enc) {
        const float* attn = (enc == 0) ? attn_e : attn_r;
        const float* table = (enc == 0) ? ent_emb : rel_emb;
        const int*   idx   = (enc == 0) ? src : erel;
        int colbase = enc * 300;

        float* F; long long fs;
        if (compact) { F = featsA; fs = DD; }
        else         { F = out + colbase; fs = OUTC; }
        hipLaunchKernelGGL(k_segmean, dim3(NN / 4), dim3(256), 0, stream,
                           table, idx, row_ptr, attn /*layer-0 weights*/, sdotA, ndotA,
                           F, fs,
                           compact ? (out + colbase) : (float*)nullptr, compact ? 1 : 0);

        for (int l = 0; l < 2; ++l) {
            int colO = colbase + (l + 1) * 100;
            const float* k3d = attn + l * 300;
            const float* k3d_next = (l == 0) ? (attn + 300) : (const float*)nullptr;
            const float* sd_in = (l == 0) ? sdotA : sdotB;
            const float* nd_in = (l == 0) ? ndotA : ndotB;
            hipLaunchKernelGGL(k_relv, dim3(NR * 64 / 256), dim3(256), 0, stream,
                               rel_norm, k3d, rdot, rwn);
            float* Fn; long long fns;
            if (compact) { Fn = (l == 0) ? featsB : featsA; fns = DD; }
            else         { Fn = out + colO; fns = OUTC; }
            hipLaunchKernelGGL(k_layer, dim3(NN / 4), dim3(256), 0, stream,
                               F, fs, rel_norm, src, erel, row_ptr,
                               sd_in, nd_in, rdot, rwn,
                               k3d_next, sdotB, ndotB,
                               Fn, fns,
                               compact ? (out + colO) : (float*)nullptr, compact ? 1 : 0);
            F = Fn; fs = fns;
        }
    }
}